// Round 3
// baseline (1727.320 us; speedup 1.0000x reference)
//
#include <hip/hip_runtime.h>

#define N_NODES 100000
#define E_EDGES 1600000
#define D 64

// ---- build per-dst linked lists: head[d] -> edge chain via next[]
__global__ void build_chain_kernel(const int* __restrict__ dst, int* __restrict__ head,
                                   int* __restrict__ next) {
    int i = blockIdx.x * 256 + threadIdx.x;
    if (i >= E_EDGES) return;
    int d = dst[i];
    int old = atomicExch(&head[d], i);
    next[i] = old;  // sequential, coalesced write
}

// ---- gather: wave handles 4 nodes, chases 4 chains concurrently; agg = mean(x[src])
__global__ void gather_kernel(const float* __restrict__ x, const int* __restrict__ src,
                              const int* __restrict__ head, const int* __restrict__ next,
                              float* __restrict__ agg, int* __restrict__ cnt) {
    int wid = (blockIdx.x * 256 + threadIdx.x) >> 6;
    int lane = threadIdx.x & 63;
    int n0 = wid * 4;
    if (n0 >= N_NODES) return;
    int eA = head[n0], eB = head[n0 + 1], eC = head[n0 + 2], eD = head[n0 + 3];
    float aA = 0.f, aB = 0.f, aC = 0.f, aD = 0.f;
    int cA = 0, cB = 0, cC = 0, cD = 0;
    while (eA >= 0 || eB >= 0 || eC >= 0 || eD >= 0) {
        if (eA >= 0) { int s = src[eA]; int nx = next[eA]; aA += x[(size_t)s * D + lane]; cA++; eA = nx; }
        if (eB >= 0) { int s = src[eB]; int nx = next[eB]; aB += x[(size_t)s * D + lane]; cB++; eB = nx; }
        if (eC >= 0) { int s = src[eC]; int nx = next[eC]; aC += x[(size_t)s * D + lane]; cC++; eC = nx; }
        if (eD >= 0) { int s = src[eD]; int nx = next[eD]; aD += x[(size_t)s * D + lane]; cD++; eD = nx; }
    }
    agg[(size_t)(n0 + 0) * D + lane] = cA ? aA * (1.0f / cA) : 0.0f;
    agg[(size_t)(n0 + 1) * D + lane] = cB ? aB * (1.0f / cB) : 0.0f;
    agg[(size_t)(n0 + 2) * D + lane] = cC ? aC * (1.0f / cC) : 0.0f;
    agg[(size_t)(n0 + 3) * D + lane] = cD ? aD * (1.0f / cD) : 0.0f;
    if (lane < 4) cnt[n0 + lane] = (lane == 0) ? cA : (lane == 1) ? cB : (lane == 2) ? cC : cD;
}

// ---- out (+)= agg @ W + (cnt>0)*b   (wave = 64 cols x 8 nodes, W in LDS, A via scalar loads)
__global__ __launch_bounds__(256) void etype_gemm_kernel(const float* __restrict__ agg,
        const int* __restrict__ cnt, const float* __restrict__ W, const float* __restrict__ bias,
        float* __restrict__ out, int first) {
    __shared__ float Wlds[D * D];
    __shared__ float blds[D];
    int tid = threadIdx.x;
    #pragma unroll
    for (int i = tid; i < D * D; i += 256) Wlds[i] = W[i];
    if (tid < D) blds[tid] = bias[tid];
    __syncthreads();
    int lane = tid & 63;
    int n0 = (blockIdx.x * 4 + (tid >> 6)) * 8;
    if (n0 >= N_NODES) return;
    float acc[8] = {0.f, 0.f, 0.f, 0.f, 0.f, 0.f, 0.f, 0.f};
    for (int k0 = 0; k0 < D; k0 += 8) {
        float w[8];
        #pragma unroll
        for (int kk = 0; kk < 8; ++kk) w[kk] = Wlds[(k0 + kk) * D + lane];
        #pragma unroll
        for (int j = 0; j < 8; ++j) {
            const float* ar = agg + (size_t)(n0 + j) * D + k0;  // wave-uniform -> s_load
            #pragma unroll
            for (int kk = 0; kk < 8; ++kk) acc[j] += ar[kk] * w[kk];
        }
    }
    #pragma unroll
    for (int j = 0; j < 8; ++j) {
        int c = cnt[n0 + j];
        float v = acc[j] + (c > 0 ? blds[lane] : 0.0f);
        size_t oi = (size_t)(n0 + j) * D + lane;
        out[oi] = first ? v : (out[oi] + v);
    }
}

extern "C" void kernel_launch(void* const* d_in, const int* in_sizes, int n_in,
                              void* d_out, int out_size, void* d_ws, size_t ws_size,
                              hipStream_t stream) {
    const float* x = (const float*)d_in[0];
    const float* W[3] = {(const float*)d_in[1], (const float*)d_in[5], (const float*)d_in[9]};
    const float* b[3] = {(const float*)d_in[2], (const float*)d_in[6], (const float*)d_in[10]};
    const int* src[3] = {(const int*)d_in[3], (const int*)d_in[7], (const int*)d_in[11]};
    const int* dst[3] = {(const int*)d_in[4], (const int*)d_in[8], (const int*)d_in[12]};
    float* out = (float*)d_out;

    char* ws = (char*)d_ws;
    size_t o = 0;
    int* head = (int*)(ws + o);  o += (size_t)N_NODES * 4;       // 0.4 MB
    int* next = (int*)(ws + o);  o += (size_t)E_EDGES * 4;       // 6.4 MB
    float* agg = (float*)(ws + o); o += (size_t)N_NODES * D * 4; // 25.6 MB
    int* cnt = (int*)(ws + o);   o += (size_t)N_NODES * 4;       // 0.4 MB

    for (int e = 0; e < 3; ++e) {
        hipMemsetAsync(head, 0xFF, (size_t)N_NODES * 4, stream);  // -1
        build_chain_kernel<<<E_EDGES / 256, 256, 0, stream>>>(dst[e], head, next);
        gather_kernel<<<N_NODES / 4 / 4, 256, 0, stream>>>(x, src[e], head, next, agg, cnt);
        etype_gemm_kernel<<<N_NODES / 8 / 4, 256, 0, stream>>>(agg, cnt, W[e], b[e], out, e == 0);
    }
}

// Round 4
// 1680.233 us; speedup vs baseline: 1.0280x; 1.0280x over previous
//
#include <hip/hip_runtime.h>

#define N_NODES 100000
#define E_EDGES 1600000
#define D 64

// ---- build 4 per-dst linked-list sub-chains per etype: head[(e*N+d)*4+k] -> chain via next
__global__ __launch_bounds__(256) void build_chain_kernel(
    const int* __restrict__ dst0, const int* __restrict__ dst1, const int* __restrict__ dst2,
    int* __restrict__ head, int* __restrict__ next) {
    int i = blockIdx.x * 256 + threadIdx.x;       // edge id, grid covers E exactly
    int e = blockIdx.y;
    const int* dst = (e == 0) ? dst0 : (e == 1) ? dst1 : dst2;
    int d = dst[i];
    int k = i & 3;                                 // sub-chain
    int old = atomicExch(&head[((size_t)e * N_NODES + d) * 4 + k], i);
    next[(size_t)e * E_EDGES + i] = old;           // coalesced sequential write
}

// ---- fused gather + GEMM: wave = 4 nodes (16 lanes x float4 each); chase 4 sub-chains/node,
//      aggregate mean(x[src]) in registers, then out_row (+)= agg @ W + (cnt>0)*b via LDS Wt.
__global__ __launch_bounds__(256) void fused_kernel(
    const float* __restrict__ x, const int* __restrict__ srcA,
    const int* __restrict__ head, const int* __restrict__ next,
    const float* __restrict__ W, const float* __restrict__ bias,
    float* __restrict__ out, int first) {
    __shared__ float Wt[D * 68];        // W transposed, row stride 68 (b128 @ 8-way floor)
    __shared__ float blds[D];
    __shared__ float aggL[4][4][D];     // [wave][node][feature]
    __shared__ int   cntL[4][4];

    int tid = threadIdx.x;
    #pragma unroll
    for (int i = tid; i < D * D; i += 256) {
        int k = i >> 6, c = i & 63;
        Wt[c * 68 + k] = W[i];          // Wt[c][k] = W[k][c]
    }
    if (tid < D) blds[tid] = bias[tid];
    __syncthreads();

    int wv = tid >> 6;
    int lane = tid & 63;
    int ndl = (tid >> 4) & 3;           // node within wave (chase phase)
    int fq = tid & 15;                  // feature quad
    int node = blockIdx.x * 16 + wv * 4 + ndl;

    const int* h = head + (size_t)node * 4;
    int e0 = h[0], e1 = h[1], e2 = h[2], e3 = h[3];   // broadcast loads (uniform per 16-lane group)
    float4 a0 = {0.f,0.f,0.f,0.f}, a1 = a0, a2 = a0, a3 = a0;
    int c0 = 0, c1 = 0, c2 = 0, c3 = 0;
    while (e0 >= 0 || e1 >= 0 || e2 >= 0 || e3 >= 0) {
        if (e0 >= 0) { int s = srcA[e0]; int nx = next[e0];
            const float4 v = *reinterpret_cast<const float4*>(x + (size_t)s * D + fq * 4);
            a0.x += v.x; a0.y += v.y; a0.z += v.z; a0.w += v.w; c0++; e0 = nx; }
        if (e1 >= 0) { int s = srcA[e1]; int nx = next[e1];
            const float4 v = *reinterpret_cast<const float4*>(x + (size_t)s * D + fq * 4);
            a1.x += v.x; a1.y += v.y; a1.z += v.z; a1.w += v.w; c1++; e1 = nx; }
        if (e2 >= 0) { int s = srcA[e2]; int nx = next[e2];
            const float4 v = *reinterpret_cast<const float4*>(x + (size_t)s * D + fq * 4);
            a2.x += v.x; a2.y += v.y; a2.z += v.z; a2.w += v.w; c2++; e2 = nx; }
        if (e3 >= 0) { int s = srcA[e3]; int nx = next[e3];
            const float4 v = *reinterpret_cast<const float4*>(x + (size_t)s * D + fq * 4);
            a3.x += v.x; a3.y += v.y; a3.z += v.z; a3.w += v.w; c3++; e3 = nx; }
    }
    int cn = c0 + c1 + c2 + c3;
    float sc = cn ? 1.0f / (float)cn : 0.0f;
    float4 m;
    m.x = (a0.x + a1.x + a2.x + a3.x) * sc;
    m.y = (a0.y + a1.y + a2.y + a3.y) * sc;
    m.z = (a0.z + a1.z + a2.z + a3.z) * sc;
    m.w = (a0.w + a1.w + a2.w + a3.w) * sc;
    *reinterpret_cast<float4*>(&aggL[wv][ndl][fq * 4]) = m;
    if (fq == 0) cntL[wv][ndl] = cn;
    __syncthreads();

    // GEMM phase: lane = output column; 4 nodes of this wave share each Wt read
    float acc0 = 0.f, acc1 = 0.f, acc2 = 0.f, acc3 = 0.f;
    #pragma unroll
    for (int k0 = 0; k0 < D; k0 += 4) {
        const float4 w4 = *reinterpret_cast<const float4*>(&Wt[lane * 68 + k0]);
        const float4 g0 = *reinterpret_cast<const float4*>(&aggL[wv][0][k0]);  // broadcast
        const float4 g1 = *reinterpret_cast<const float4*>(&aggL[wv][1][k0]);
        const float4 g2 = *reinterpret_cast<const float4*>(&aggL[wv][2][k0]);
        const float4 g3 = *reinterpret_cast<const float4*>(&aggL[wv][3][k0]);
        acc0 += g0.x * w4.x + g0.y * w4.y + g0.z * w4.z + g0.w * w4.w;
        acc1 += g1.x * w4.x + g1.y * w4.y + g1.z * w4.z + g1.w * w4.w;
        acc2 += g2.x * w4.x + g2.y * w4.y + g2.z * w4.z + g2.w * w4.w;
        acc3 += g3.x * w4.x + g3.y * w4.y + g3.z * w4.z + g3.w * w4.w;
    }
    int base = blockIdx.x * 16 + wv * 4;
    float v0 = acc0 + (cntL[wv][0] > 0 ? blds[lane] : 0.0f);
    float v1 = acc1 + (cntL[wv][1] > 0 ? blds[lane] : 0.0f);
    float v2 = acc2 + (cntL[wv][2] > 0 ? blds[lane] : 0.0f);
    float v3 = acc3 + (cntL[wv][3] > 0 ? blds[lane] : 0.0f);
    size_t o0 = (size_t)base * D + lane;
    if (first) {
        out[o0]           = v0;
        out[o0 + D]       = v1;
        out[o0 + 2 * D]   = v2;
        out[o0 + 3 * D]   = v3;
    } else {
        out[o0]           += v0;
        out[o0 + D]       += v1;
        out[o0 + 2 * D]   += v2;
        out[o0 + 3 * D]   += v3;
    }
}

extern "C" void kernel_launch(void* const* d_in, const int* in_sizes, int n_in,
                              void* d_out, int out_size, void* d_ws, size_t ws_size,
                              hipStream_t stream) {
    const float* x = (const float*)d_in[0];
    const float* W[3] = {(const float*)d_in[1], (const float*)d_in[5], (const float*)d_in[9]};
    const float* b[3] = {(const float*)d_in[2], (const float*)d_in[6], (const float*)d_in[10]};
    const int* src[3] = {(const int*)d_in[3], (const int*)d_in[7], (const int*)d_in[11]};
    const int* dst[3] = {(const int*)d_in[4], (const int*)d_in[8], (const int*)d_in[12]};
    float* out = (float*)d_out;

    char* ws = (char*)d_ws;
    size_t o = 0;
    int* head = (int*)(ws + o); o += (size_t)3 * N_NODES * 4 * 4;   // 4.8 MB (3 etypes x 4 sub-chains)
    int* next = (int*)(ws + o); o += (size_t)3 * E_EDGES * 4;       // 19.2 MB

    hipMemsetAsync(head, 0xFF, (size_t)3 * N_NODES * 4 * 4, stream);  // all -1

    dim3 bgrid(E_EDGES / 256, 3);
    build_chain_kernel<<<bgrid, 256, 0, stream>>>(dst[0], dst[1], dst[2], head, next);

    for (int e = 0; e < 3; ++e) {
        fused_kernel<<<N_NODES / 16, 256, 0, stream>>>(
            x, src[e],
            head + (size_t)e * N_NODES * 4,
            next + (size_t)e * E_EDGES,
            W[e], b[e], out, e == 0);
    }
}

// Round 5
// 1004.841 us; speedup vs baseline: 1.7190x; 1.6721x over previous
//
#include <hip/hip_runtime.h>

#define N_NODES 100000
#define E_EDGES 1600000
#define D 64

// ---- build: packed edge list {src, next} + 4 per-dst sub-chains + degree
__global__ __launch_bounds__(256) void build_kernel(
    const int* __restrict__ src, const int* __restrict__ dst,
    int* __restrict__ head, int2* __restrict__ elist, unsigned* __restrict__ deg) {
    int i = blockIdx.x * 256 + threadIdx.x;        // grid covers E exactly
    int d = dst[i];
    int s = src[i];
    int old = atomicExch(&head[(size_t)d * 4 + (i & 3)], i);
    elist[i] = make_int2(s, old);                  // coalesced 8B write
    atomicAdd(&deg[d], 1u);
}

// ---- compact: thread per node; chase 4 sub-chains, write src ids sequentially
__global__ __launch_bounds__(256) void compact_kernel(
    const int2* __restrict__ elist, const int* __restrict__ head,
    const unsigned* __restrict__ deg, int* __restrict__ csr,
    unsigned* __restrict__ off, unsigned* __restrict__ cnt,
    unsigned* __restrict__ cursor) {
    int id = blockIdx.x * 256 + threadIdx.x;
    if (id >= N_NODES) return;
    unsigned c = deg[id];
    cnt[id] = c;
    unsigned start = c ? atomicAdd(cursor, c) : 0u;
    off[id] = start;
    if (!c) return;
    int e0 = head[id * 4 + 0], e1 = head[id * 4 + 1];
    int e2 = head[id * 4 + 2], e3 = head[id * 4 + 3];
    int* o = csr + start;                          // thread-local sequential writes
    while (e0 >= 0 || e1 >= 0 || e2 >= 0 || e3 >= 0) {
        if (e0 >= 0) { int2 v = elist[e0]; *o++ = v.x; e0 = v.y; }
        if (e1 >= 0) { int2 v = elist[e1]; *o++ = v.x; e1 = v.y; }
        if (e2 >= 0) { int2 v = elist[e2]; *o++ = v.x; e2 = v.y; }
        if (e3 >= 0) { int2 v = elist[e3]; *o++ = v.x; e3 = v.y; }
    }
}

// ---- gather + transform: wave per node; mean(x[srcs]) then @W + b, W in registers
__global__ __launch_bounds__(256) void gather_xform_kernel(
    const float* __restrict__ x, const int* __restrict__ csr,
    const unsigned* __restrict__ off, const unsigned* __restrict__ cnt,
    const float* __restrict__ W, const float* __restrict__ bias,
    float* __restrict__ out, int first) {
    int wid = (blockIdx.x * 256 + threadIdx.x) >> 6;   // node (grid exact)
    int lane = threadIdx.x & 63;
    unsigned c = cnt[wid];
    size_t orow = (size_t)wid * D + lane;
    if (c == 0) { if (first) out[orow] = 0.0f; return; }

    float w[D];                                        // W column for this lane
    #pragma unroll
    for (int k = 0; k < D; ++k) w[k] = W[k * D + lane];
    float bl = bias[lane];

    const int* idx = csr + off[wid];
    float a0 = 0.f, a1 = 0.f, a2 = 0.f, a3 = 0.f, a4 = 0.f, a5 = 0.f, a6 = 0.f, a7 = 0.f;
    if (c <= 64) {
        // indices in one coalesced load, broadcast via readlane (SGPR x-addressing)
        int my = (lane < (int)c) ? idx[lane] : 0;      // csr padded +64 ints for tail
        unsigned j = 0;
        for (; j + 8 <= c; j += 8) {
            int s0 = __builtin_amdgcn_readlane(my, j + 0);
            int s1 = __builtin_amdgcn_readlane(my, j + 1);
            int s2 = __builtin_amdgcn_readlane(my, j + 2);
            int s3 = __builtin_amdgcn_readlane(my, j + 3);
            int s4 = __builtin_amdgcn_readlane(my, j + 4);
            int s5 = __builtin_amdgcn_readlane(my, j + 5);
            int s6 = __builtin_amdgcn_readlane(my, j + 6);
            int s7 = __builtin_amdgcn_readlane(my, j + 7);
            a0 += x[(size_t)s0 * D + lane];
            a1 += x[(size_t)s1 * D + lane];
            a2 += x[(size_t)s2 * D + lane];
            a3 += x[(size_t)s3 * D + lane];
            a4 += x[(size_t)s4 * D + lane];
            a5 += x[(size_t)s5 * D + lane];
            a6 += x[(size_t)s6 * D + lane];
            a7 += x[(size_t)s7 * D + lane];
        }
        for (; j < c; ++j)
            a0 += x[(size_t)__builtin_amdgcn_readlane(my, j) * D + lane];
    } else {
        unsigned j = 0;
        for (; j + 8 <= c; j += 8) {
            int s0 = idx[j + 0], s1 = idx[j + 1], s2 = idx[j + 2], s3 = idx[j + 3];
            int s4 = idx[j + 4], s5 = idx[j + 5], s6 = idx[j + 6], s7 = idx[j + 7];
            a0 += x[(size_t)s0 * D + lane];
            a1 += x[(size_t)s1 * D + lane];
            a2 += x[(size_t)s2 * D + lane];
            a3 += x[(size_t)s3 * D + lane];
            a4 += x[(size_t)s4 * D + lane];
            a5 += x[(size_t)s5 * D + lane];
            a6 += x[(size_t)s6 * D + lane];
            a7 += x[(size_t)s7 * D + lane];
        }
        for (; j < c; ++j) a0 += x[(size_t)idx[j] * D + lane];
    }
    float m = (((a0 + a1) + (a2 + a3)) + ((a4 + a5) + (a6 + a7))) * (1.0f / (float)c);

    // out_col(lane) = sum_k m_k * W[k][lane]  via readlane broadcast of m
    float acc = 0.f;
    #pragma unroll
    for (int k = 0; k < D; ++k) {
        float mk = __uint_as_float(__builtin_amdgcn_readlane(__float_as_uint(m), k));
        acc = fmaf(mk, w[k], acc);
    }
    float v = acc + bl;
    if (first) out[orow] = v;
    else       out[orow] += v;
}

extern "C" void kernel_launch(void* const* d_in, const int* in_sizes, int n_in,
                              void* d_out, int out_size, void* d_ws, size_t ws_size,
                              hipStream_t stream) {
    const float* x = (const float*)d_in[0];
    const float* W[3] = {(const float*)d_in[1], (const float*)d_in[5], (const float*)d_in[9]};
    const float* b[3] = {(const float*)d_in[2], (const float*)d_in[6], (const float*)d_in[10]};
    const int* src[3] = {(const int*)d_in[3], (const int*)d_in[7], (const int*)d_in[11]};
    const int* dst[3] = {(const int*)d_in[4], (const int*)d_in[8], (const int*)d_in[12]};
    float* out = (float*)d_out;

    char* ws = (char*)d_ws;
    size_t o = 0;
    int2* elist = (int2*)(ws + o);    o += (size_t)E_EDGES * 8;          // 12.8 MB
    int* head = (int*)(ws + o);       o += (size_t)N_NODES * 4 * 4;      // 1.6 MB
    unsigned* deg = (unsigned*)(ws + o); o += (size_t)N_NODES * 4 + 64;  // deg + cursor
    unsigned* cursor = deg + N_NODES;
    unsigned* off = (unsigned*)(ws + o); o += (size_t)N_NODES * 4;
    unsigned* cnt = (unsigned*)(ws + o); o += (size_t)N_NODES * 4;
    int* csr = (int*)(ws + o);        o += (size_t)(E_EDGES + 64) * 4;   // +64 pad for idx[lane] tail

    for (int e = 0; e < 3; ++e) {
        hipMemsetAsync(head, 0xFF, (size_t)N_NODES * 4 * 4, stream);
        hipMemsetAsync(deg, 0, (size_t)N_NODES * 4 + 64, stream);
        build_kernel<<<E_EDGES / 256, 256, 0, stream>>>(src[e], dst[e], head, elist, deg);
        compact_kernel<<<(N_NODES + 255) / 256, 256, 0, stream>>>(elist, head, deg, csr, off, cnt, cursor);
        gather_xform_kernel<<<N_NODES / 4, 256, 0, stream>>>(x, csr, off, cnt, W[e], b[e], out, e == 0);
    }
}

// Round 6
// 497.883 us; speedup vs baseline: 3.4693x; 2.0182x over previous
//
#include <hip/hip_runtime.h>

#define N_NODES 100000
#define E_EDGES 1600000
#define D 64
#define NB 256                         // buckets
#define BW 391                         // bucket width: 391*256 = 100096 >= N
#define EPB 2048                       // edges per binning block
#define NBLK ((E_EDGES + EPB - 1) / EPB)   // 782
#define CAP 8192                       // per-bucket LDS staging capacity

// ---- kA: per-block per-bucket histogram (coalesced writes, LDS atomics only)
__global__ __launch_bounds__(256) void hist_kernel(
    const int* __restrict__ dst0, const int* __restrict__ dst1, const int* __restrict__ dst2,
    unsigned* __restrict__ bh) {
    __shared__ unsigned h[NB];
    int t = threadIdx.x, blk = blockIdx.x, e = blockIdx.y;
    const int* dst = (e == 0) ? dst0 : (e == 1) ? dst1 : dst2;
    h[t] = 0;
    __syncthreads();
    int base = blk * EPB;
    #pragma unroll
    for (int r = 0; r < EPB / 256; ++r) {
        int i = base + r * 256 + t;
        if (i < E_EDGES) atomicAdd(&h[(unsigned)dst[i] / BW], 1u);
    }
    __syncthreads();
    bh[((size_t)e * NBLK + blk) * NB + t] = h[t];
}

// ---- kB: exclusive scan down each bucket column of bh (in place) + bucket totals
__global__ __launch_bounds__(256) void colscan_kernel(
    unsigned* __restrict__ bh, unsigned* __restrict__ total) {
    __shared__ unsigned sa[1024], sb[1024];
    int t = threadIdx.x, b = blockIdx.x, e = blockIdx.y;
    unsigned orig[4];
    #pragma unroll
    for (int k = 0; k < 4; ++k) {
        int i = t + k * 256;
        unsigned v = (i < NBLK) ? bh[((size_t)e * NBLK + i) * NB + b] : 0u;
        orig[k] = v;
        sa[i] = v;
    }
    __syncthreads();
    unsigned* s = sa; unsigned* d = sb;
    for (int st = 1; st < 1024; st <<= 1) {
        #pragma unroll
        for (int k = 0; k < 4; ++k) {
            int i = t + k * 256;
            d[i] = s[i] + ((i >= st) ? s[i - st] : 0u);
        }
        __syncthreads();
        unsigned* tmp = s; s = d; d = tmp;
    }
    #pragma unroll
    for (int k = 0; k < 4; ++k) {
        int i = t + k * 256;
        if (i < NBLK) bh[((size_t)e * NBLK + i) * NB + b] = s[i] - orig[k];
    }
    if (t == 0) total[e * NB + b] = s[1023];
}

// ---- kC: bucket bases = exclusive scan of totals (per etype)
__global__ __launch_bounds__(256) void basescan_kernel(
    const unsigned* __restrict__ total, unsigned* __restrict__ bases) {
    __shared__ unsigned sa[NB], sb[NB];
    int t = threadIdx.x;
    for (int e = 0; e < 3; ++e) {
        unsigned v = total[e * NB + t];
        sa[t] = v;
        __syncthreads();
        unsigned* s = sa; unsigned* d = sb;
        for (int st = 1; st < NB; st <<= 1) {
            d[t] = s[t] + ((t >= st) ? s[t - st] : 0u);
            __syncthreads();
            unsigned* tmp = s; s = d; d = tmp;
        }
        bases[e * NB + t] = s[t] - v;
        __syncthreads();
    }
}

// ---- kD: binning scatter; pos = base + block-offset + LDS rank; packed {dloc,src}
__global__ __launch_bounds__(256) void bin_kernel(
    const int* __restrict__ s0, const int* __restrict__ s1, const int* __restrict__ s2,
    const int* __restrict__ d0, const int* __restrict__ d1, const int* __restrict__ d2,
    const unsigned* __restrict__ bh, const unsigned* __restrict__ bases,
    unsigned* __restrict__ binned) {
    __shared__ unsigned basel[NB];
    __shared__ unsigned lc[NB];
    int t = threadIdx.x, blk = blockIdx.x, e = blockIdx.y;
    const int* src_ = (e == 0) ? s0 : (e == 1) ? s1 : s2;
    const int* dst_ = (e == 0) ? d0 : (e == 1) ? d1 : d2;
    basel[t] = bases[e * NB + t] + bh[((size_t)e * NBLK + blk) * NB + t];
    lc[t] = 0;
    __syncthreads();
    int base = blk * EPB;
    #pragma unroll
    for (int r = 0; r < EPB / 256; ++r) {
        int i = base + r * 256 + t;
        if (i < E_EDGES) {
            unsigned dd = (unsigned)dst_[i];
            unsigned b = dd / BW;
            unsigned dloc = dd - b * BW;
            unsigned rank = atomicAdd(&lc[b], 1u);
            binned[(size_t)e * E_EDGES + basel[b] + rank] = (unsigned)src_[i] | (dloc << 17);
        }
    }
}

// ---- kE: per-bucket CSR build fully in LDS, coalesced dump
__global__ __launch_bounds__(256) void csr_kernel(
    const unsigned* __restrict__ binned, const unsigned* __restrict__ total,
    const unsigned* __restrict__ bases, int* __restrict__ csr,
    unsigned* __restrict__ off, unsigned* __restrict__ cnt, int e) {
    __shared__ unsigned lh[512], sa[512], sb[512];
    __shared__ unsigned loff[BW + 1], lc[BW + 1];
    __shared__ int cl[CAP];
    int t = threadIdx.x, b = blockIdx.x;
    unsigned n = total[e * NB + b];
    unsigned g = bases[e * NB + b];
    lh[t] = 0; lh[t + 256] = 0;
    for (int j = t; j < BW + 1; j += 256) lc[j] = 0;
    __syncthreads();
    const unsigned* bp = binned + (size_t)e * E_EDGES + g;
    for (unsigned i = t; i < n; i += 256) atomicAdd(&lh[bp[i] >> 17], 1u);
    __syncthreads();
    sa[t] = lh[t]; sa[t + 256] = lh[t + 256];
    __syncthreads();
    unsigned* s = sa; unsigned* d = sb;
    for (int st = 1; st < 512; st <<= 1) {
        d[t] = s[t] + ((t >= st) ? s[t - st] : 0u);
        int i2 = t + 256;
        d[i2] = s[i2] + ((i2 >= st) ? s[i2 - st] : 0u);
        __syncthreads();
        unsigned* tmp = s; s = d; d = tmp;
    }
    if (t < BW + 1 - 256) loff[t + 256] = s[t + 256] - lh[t + 256];
    loff[t] = s[t] - lh[t];
    __syncthreads();
    if (n <= CAP) {
        for (unsigned i = t; i < n; i += 256) {
            unsigned v = bp[i];
            unsigned dl = v >> 17;
            unsigned r = atomicAdd(&lc[dl], 1u);
            cl[loff[dl] + r] = (int)(v & 0x1FFFFu);
        }
        __syncthreads();
        for (unsigned i = t; i < n; i += 256) csr[g + i] = cl[i];
    } else {  // statistically impossible overflow fallback (correct, slower)
        for (unsigned i = t; i < n; i += 256) {
            unsigned v = bp[i];
            unsigned dl = v >> 17;
            unsigned r = atomicAdd(&lc[dl], 1u);
            csr[g + loff[dl] + r] = (int)(v & 0x1FFFFu);
        }
    }
    int node0 = b * BW;
    for (int j = t; j < BW; j += 256) {
        int nd = node0 + j;
        if (nd < N_NODES) {
            off[nd] = g + loff[j];
            cnt[nd] = lh[j];
        }
    }
}

// ---- gather + transform: wave per node; mean(x[srcs]) then @W + b, W in registers
__global__ __launch_bounds__(256) void gather_xform_kernel(
    const float* __restrict__ x, const int* __restrict__ csr,
    const unsigned* __restrict__ off, const unsigned* __restrict__ cnt,
    const float* __restrict__ W, const float* __restrict__ bias,
    float* __restrict__ out, int first) {
    int wid = (blockIdx.x * 256 + threadIdx.x) >> 6;
    int lane = threadIdx.x & 63;
    unsigned c = cnt[wid];
    size_t orow = (size_t)wid * D + lane;
    if (c == 0) { if (first) out[orow] = 0.0f; return; }

    float w[D];
    #pragma unroll
    for (int k = 0; k < D; ++k) w[k] = W[k * D + lane];
    float bl = bias[lane];

    const int* idx = csr + off[wid];
    float a0 = 0.f, a1 = 0.f, a2 = 0.f, a3 = 0.f, a4 = 0.f, a5 = 0.f, a6 = 0.f, a7 = 0.f;
    if (c <= 64) {
        int my = (lane < (int)c) ? idx[lane] : 0;
        unsigned j = 0;
        for (; j + 8 <= c; j += 8) {
            int s0 = __builtin_amdgcn_readlane(my, j + 0);
            int s1 = __builtin_amdgcn_readlane(my, j + 1);
            int s2 = __builtin_amdgcn_readlane(my, j + 2);
            int s3 = __builtin_amdgcn_readlane(my, j + 3);
            int s4 = __builtin_amdgcn_readlane(my, j + 4);
            int s5 = __builtin_amdgcn_readlane(my, j + 5);
            int s6 = __builtin_amdgcn_readlane(my, j + 6);
            int s7 = __builtin_amdgcn_readlane(my, j + 7);
            a0 += x[(size_t)s0 * D + lane];
            a1 += x[(size_t)s1 * D + lane];
            a2 += x[(size_t)s2 * D + lane];
            a3 += x[(size_t)s3 * D + lane];
            a4 += x[(size_t)s4 * D + lane];
            a5 += x[(size_t)s5 * D + lane];
            a6 += x[(size_t)s6 * D + lane];
            a7 += x[(size_t)s7 * D + lane];
        }
        for (; j < c; ++j)
            a0 += x[(size_t)__builtin_amdgcn_readlane(my, j) * D + lane];
    } else {
        unsigned j = 0;
        for (; j + 8 <= c; j += 8) {
            int s0 = idx[j + 0], s1 = idx[j + 1], s2 = idx[j + 2], s3 = idx[j + 3];
            int s4 = idx[j + 4], s5 = idx[j + 5], s6 = idx[j + 6], s7 = idx[j + 7];
            a0 += x[(size_t)s0 * D + lane];
            a1 += x[(size_t)s1 * D + lane];
            a2 += x[(size_t)s2 * D + lane];
            a3 += x[(size_t)s3 * D + lane];
            a4 += x[(size_t)s4 * D + lane];
            a5 += x[(size_t)s5 * D + lane];
            a6 += x[(size_t)s6 * D + lane];
            a7 += x[(size_t)s7 * D + lane];
        }
        for (; j < c; ++j) a0 += x[(size_t)idx[j] * D + lane];
    }
    float m = (((a0 + a1) + (a2 + a3)) + ((a4 + a5) + (a6 + a7))) * (1.0f / (float)c);

    float acc = 0.f;
    #pragma unroll
    for (int k = 0; k < D; ++k) {
        float mk = __uint_as_float(__builtin_amdgcn_readlane(__float_as_uint(m), k));
        acc = fmaf(mk, w[k], acc);
    }
    float v = acc + bl;
    if (first) out[orow] = v;
    else       out[orow] += v;
}

extern "C" void kernel_launch(void* const* d_in, const int* in_sizes, int n_in,
                              void* d_out, int out_size, void* d_ws, size_t ws_size,
                              hipStream_t stream) {
    const float* x = (const float*)d_in[0];
    const float* W[3] = {(const float*)d_in[1], (const float*)d_in[5], (const float*)d_in[9]};
    const float* b[3] = {(const float*)d_in[2], (const float*)d_in[6], (const float*)d_in[10]};
    const int* src[3] = {(const int*)d_in[3], (const int*)d_in[7], (const int*)d_in[11]};
    const int* dst[3] = {(const int*)d_in[4], (const int*)d_in[8], (const int*)d_in[12]};
    float* out = (float*)d_out;

    char* ws = (char*)d_ws;
    size_t o = 0;
    unsigned* bh = (unsigned*)(ws + o);     o += (size_t)3 * NBLK * NB * 4;   // 2.4 MB
    unsigned* total = (unsigned*)(ws + o);  o += (size_t)3 * NB * 4;
    unsigned* bases = (unsigned*)(ws + o);  o += (size_t)3 * NB * 4;
    unsigned* binned = (unsigned*)(ws + o); o += (size_t)3 * E_EDGES * 4;     // 19.2 MB
    int* csr = (int*)(ws + o);              o += (size_t)(E_EDGES + 64) * 4;  // 6.4 MB
    unsigned* off = (unsigned*)(ws + o);    o += (size_t)N_NODES * 4;
    unsigned* cnt = (unsigned*)(ws + o);    o += (size_t)N_NODES * 4;

    dim3 gE(NBLK, 3);
    hist_kernel<<<gE, 256, 0, stream>>>(dst[0], dst[1], dst[2], bh);
    dim3 gC(NB, 3);
    colscan_kernel<<<gC, 256, 0, stream>>>(bh, total);
    basescan_kernel<<<1, 256, 0, stream>>>(total, bases);
    bin_kernel<<<gE, 256, 0, stream>>>(src[0], src[1], src[2], dst[0], dst[1], dst[2],
                                       bh, bases, binned);
    for (int e = 0; e < 3; ++e) {
        csr_kernel<<<NB, 256, 0, stream>>>(binned, total, bases, csr, off, cnt, e);
        gather_xform_kernel<<<N_NODES / 4, 256, 0, stream>>>(x, csr, off, cnt, W[e], b[e], out, e == 0);
    }
}

// Round 7
// 294.674 us; speedup vs baseline: 5.8618x; 1.6896x over previous
//
#include <hip/hip_runtime.h>

#define N_NODES 100000
#define E_EDGES 1600000
#define D 64
#define NB 256                         // buckets
#define BW 391                         // bucket width: 391*256 = 100096 >= N
#define EPB 2048                       // edges per binning block
#define NBLK ((E_EDGES + EPB - 1) / EPB)   // 782
#define CAP 8192                       // per-bucket LDS staging capacity
#define CSR_STRIDE (E_EDGES + 64)

// ---- kA: per-block per-bucket histogram (coalesced writes, LDS atomics only)
__global__ __launch_bounds__(256) void hist_kernel(
    const int* __restrict__ dst0, const int* __restrict__ dst1, const int* __restrict__ dst2,
    unsigned* __restrict__ bh) {
    __shared__ unsigned h[NB];
    int t = threadIdx.x, blk = blockIdx.x, e = blockIdx.y;
    const int* dst = (e == 0) ? dst0 : (e == 1) ? dst1 : dst2;
    h[t] = 0;
    __syncthreads();
    int base = blk * EPB;
    #pragma unroll
    for (int r = 0; r < EPB / 256; ++r) {
        int i = base + r * 256 + t;
        if (i < E_EDGES) atomicAdd(&h[(unsigned)dst[i] / BW], 1u);
    }
    __syncthreads();
    bh[((size_t)e * NBLK + blk) * NB + t] = h[t];
}

// ---- kB: exclusive scan down each bucket column of bh (in place) + bucket totals
__global__ __launch_bounds__(256) void colscan_kernel(
    unsigned* __restrict__ bh, unsigned* __restrict__ total) {
    __shared__ unsigned sa[1024], sb[1024];
    int t = threadIdx.x, b = blockIdx.x, e = blockIdx.y;
    unsigned orig[4];
    #pragma unroll
    for (int k = 0; k < 4; ++k) {
        int i = t + k * 256;
        unsigned v = (i < NBLK) ? bh[((size_t)e * NBLK + i) * NB + b] : 0u;
        orig[k] = v;
        sa[i] = v;
    }
    __syncthreads();
    unsigned* s = sa; unsigned* d = sb;
    for (int st = 1; st < 1024; st <<= 1) {
        #pragma unroll
        for (int k = 0; k < 4; ++k) {
            int i = t + k * 256;
            d[i] = s[i] + ((i >= st) ? s[i - st] : 0u);
        }
        __syncthreads();
        unsigned* tmp = s; s = d; d = tmp;
    }
    #pragma unroll
    for (int k = 0; k < 4; ++k) {
        int i = t + k * 256;
        if (i < NBLK) bh[((size_t)e * NBLK + i) * NB + b] = s[i] - orig[k];
    }
    if (t == 0) total[e * NB + b] = s[1023];
}

// ---- kC: bucket bases = exclusive scan of totals (per etype)
__global__ __launch_bounds__(256) void basescan_kernel(
    const unsigned* __restrict__ total, unsigned* __restrict__ bases) {
    __shared__ unsigned sa[NB], sb[NB];
    int t = threadIdx.x;
    for (int e = 0; e < 3; ++e) {
        unsigned v = total[e * NB + t];
        sa[t] = v;
        __syncthreads();
        unsigned* s = sa; unsigned* d = sb;
        for (int st = 1; st < NB; st <<= 1) {
            d[t] = s[t] + ((t >= st) ? s[t - st] : 0u);
            __syncthreads();
            unsigned* tmp = s; s = d; d = tmp;
        }
        bases[e * NB + t] = s[t] - v;
        __syncthreads();
    }
}

// ---- kD: binning scatter; pos = base + block-offset + LDS rank; packed {dloc,src}
__global__ __launch_bounds__(256) void bin_kernel(
    const int* __restrict__ s0, const int* __restrict__ s1, const int* __restrict__ s2,
    const int* __restrict__ d0, const int* __restrict__ d1, const int* __restrict__ d2,
    const unsigned* __restrict__ bh, const unsigned* __restrict__ bases,
    unsigned* __restrict__ binned) {
    __shared__ unsigned basel[NB];
    __shared__ unsigned lc[NB];
    int t = threadIdx.x, blk = blockIdx.x, e = blockIdx.y;
    const int* src_ = (e == 0) ? s0 : (e == 1) ? s1 : s2;
    const int* dst_ = (e == 0) ? d0 : (e == 1) ? d1 : d2;
    basel[t] = bases[e * NB + t] + bh[((size_t)e * NBLK + blk) * NB + t];
    lc[t] = 0;
    __syncthreads();
    int base = blk * EPB;
    #pragma unroll
    for (int r = 0; r < EPB / 256; ++r) {
        int i = base + r * 256 + t;
        if (i < E_EDGES) {
            unsigned dd = (unsigned)dst_[i];
            unsigned b = dd / BW;
            unsigned dloc = dd - b * BW;
            unsigned rank = atomicAdd(&lc[b], 1u);
            binned[(size_t)e * E_EDGES + basel[b] + rank] = (unsigned)src_[i] | (dloc << 17);
        }
    }
}

// ---- kE: per-bucket CSR build fully in LDS, coalesced dump (grid.y = etype)
__global__ __launch_bounds__(256) void csr_kernel(
    const unsigned* __restrict__ binned, const unsigned* __restrict__ total,
    const unsigned* __restrict__ bases, int* __restrict__ csr,
    unsigned* __restrict__ off, unsigned* __restrict__ cnt) {
    __shared__ unsigned lh[512], sa[512], sb[512];
    __shared__ unsigned loff[BW + 1], lc[BW + 1];
    __shared__ int cl[CAP];
    int t = threadIdx.x, b = blockIdx.x, e = blockIdx.y;
    unsigned n = total[e * NB + b];
    unsigned g = bases[e * NB + b];
    lh[t] = 0; lh[t + 256] = 0;
    for (int j = t; j < BW + 1; j += 256) lc[j] = 0;
    __syncthreads();
    const unsigned* bp = binned + (size_t)e * E_EDGES + g;
    for (unsigned i = t; i < n; i += 256) atomicAdd(&lh[bp[i] >> 17], 1u);
    __syncthreads();
    sa[t] = lh[t]; sa[t + 256] = lh[t + 256];
    __syncthreads();
    unsigned* s = sa; unsigned* d = sb;
    for (int st = 1; st < 512; st <<= 1) {
        d[t] = s[t] + ((t >= st) ? s[t - st] : 0u);
        int i2 = t + 256;
        d[i2] = s[i2] + ((i2 >= st) ? s[i2 - st] : 0u);
        __syncthreads();
        unsigned* tmp = s; s = d; d = tmp;
    }
    if (t < BW + 1 - 256) loff[t + 256] = s[t + 256] - lh[t + 256];
    loff[t] = s[t] - lh[t];
    __syncthreads();
    int* csre = csr + (size_t)e * CSR_STRIDE;
    if (n <= CAP) {
        for (unsigned i = t; i < n; i += 256) {
            unsigned v = bp[i];
            unsigned dl = v >> 17;
            unsigned r = atomicAdd(&lc[dl], 1u);
            cl[loff[dl] + r] = (int)(v & 0x1FFFFu);
        }
        __syncthreads();
        for (unsigned i = t; i < n; i += 256) csre[g + i] = cl[i];
    } else {  // statistically impossible overflow fallback (correct, slower)
        for (unsigned i = t; i < n; i += 256) {
            unsigned v = bp[i];
            unsigned dl = v >> 17;
            unsigned r = atomicAdd(&lc[dl], 1u);
            csre[g + loff[dl] + r] = (int)(v & 0x1FFFFu);
        }
    }
    int node0 = b * BW;
    for (int j = t; j < BW; j += 256) {
        int nd = node0 + j;
        if (nd < N_NODES) {
            off[e * N_NODES + nd] = g + loff[j];
            cnt[e * N_NODES + nd] = lh[j];
        }
    }
}

// ---- convert x rows to packed bf16x2 (RNE): xh[n*32+p] = {bf16(x[2p]), bf16(x[2p+1])}
__global__ __launch_bounds__(256) void convert_kernel(const float* __restrict__ x,
                                                      unsigned* __restrict__ xh) {
    int i = blockIdx.x * 256 + threadIdx.x;    // pair index; grid covers N*32 exactly
    float2 v = *reinterpret_cast<const float2*>(x + (size_t)i * 2);
    unsigned lo = __float_as_uint(v.x), hi = __float_as_uint(v.y);
    lo = (lo + 0x7FFFu + ((lo >> 16) & 1u)) >> 16;
    hi = (hi + 0x7FFFu + ((hi >> 16) & 1u)) & 0xFFFF0000u;
    xh[i] = lo | hi;
}

// ---- fused gather+transform, all 3 etypes: half-wave (32 lanes) per node, lane = feature pair
__global__ __launch_bounds__(256) void gather_fused_kernel(
    const unsigned* __restrict__ xh, const int* __restrict__ csr,
    const unsigned* __restrict__ off, const unsigned* __restrict__ cnt,
    const float* __restrict__ W0, const float* __restrict__ W1, const float* __restrict__ W2,
    const float* __restrict__ b0, const float* __restrict__ b1, const float* __restrict__ b2,
    float* __restrict__ out) {
    __shared__ float aggL[8][D];
    __shared__ int cntL[8];

    int tid = threadIdx.x;
    int hw = tid >> 5, l = tid & 31;       // half-wave id (node slot), lane-in-half
    int wv = tid >> 6, lane = tid & 63;    // wave id, lane (transform phase)
    int nodebase = blockIdx.x * 8;

    float acc0 = 0.f, acc1 = 0.f;          // out accumulators: nodes 2wv, 2wv+1, col=lane

    for (int e = 0; e < 3; ++e) {
        const float* W = (e == 0) ? W0 : (e == 1) ? W1 : W2;
        const float* bias = (e == 0) ? b0 : (e == 1) ? b1 : b2;

        int node = nodebase + hw;
        unsigned c = cnt[e * N_NODES + node];
        const int* idx = csr + (size_t)e * CSR_STRIDE + off[e * N_NODES + node];

        float s0 = 0.f, s1 = 0.f, s2 = 0.f, s3 = 0.f;   // feature 2l accumulators
        float s4 = 0.f, s5 = 0.f, s6 = 0.f, s7 = 0.f;
        float t0 = 0.f, t1 = 0.f, t2 = 0.f, t3 = 0.f;   // feature 2l+1 accumulators
        float t4 = 0.f, t5 = 0.f, t6 = 0.f, t7 = 0.f;
        unsigned j = 0;
        for (; j + 8 <= c; j += 8) {
            int i0 = idx[j + 0], i1 = idx[j + 1], i2 = idx[j + 2], i3 = idx[j + 3];
            int i4 = idx[j + 4], i5 = idx[j + 5], i6 = idx[j + 6], i7 = idx[j + 7];
            unsigned u0 = xh[(size_t)i0 * 32 + l];
            unsigned u1 = xh[(size_t)i1 * 32 + l];
            unsigned u2 = xh[(size_t)i2 * 32 + l];
            unsigned u3 = xh[(size_t)i3 * 32 + l];
            unsigned u4 = xh[(size_t)i4 * 32 + l];
            unsigned u5 = xh[(size_t)i5 * 32 + l];
            unsigned u6 = xh[(size_t)i6 * 32 + l];
            unsigned u7 = xh[(size_t)i7 * 32 + l];
            s0 += __uint_as_float(u0 << 16); t0 += __uint_as_float(u0 & 0xFFFF0000u);
            s1 += __uint_as_float(u1 << 16); t1 += __uint_as_float(u1 & 0xFFFF0000u);
            s2 += __uint_as_float(u2 << 16); t2 += __uint_as_float(u2 & 0xFFFF0000u);
            s3 += __uint_as_float(u3 << 16); t3 += __uint_as_float(u3 & 0xFFFF0000u);
            s4 += __uint_as_float(u4 << 16); t4 += __uint_as_float(u4 & 0xFFFF0000u);
            s5 += __uint_as_float(u5 << 16); t5 += __uint_as_float(u5 & 0xFFFF0000u);
            s6 += __uint_as_float(u6 << 16); t6 += __uint_as_float(u6 & 0xFFFF0000u);
            s7 += __uint_as_float(u7 << 16); t7 += __uint_as_float(u7 & 0xFFFF0000u);
        }
        for (; j < c; ++j) {
            int i0 = idx[j];
            unsigned u0 = xh[(size_t)i0 * 32 + l];
            s0 += __uint_as_float(u0 << 16);
            t0 += __uint_as_float(u0 & 0xFFFF0000u);
        }
        float sc = c ? 1.0f / (float)c : 0.0f;
        float m0 = (((s0 + s1) + (s2 + s3)) + ((s4 + s5) + (s6 + s7))) * sc;
        float m1 = (((t0 + t1) + (t2 + t3)) + ((t4 + t5) + (t6 + t7))) * sc;
        *reinterpret_cast<float2*>(&aggL[hw][2 * l]) = make_float2(m0, m1);
        if (l == 0) cntL[hw] = (int)c;
        __syncthreads();

        // transform: wave wv handles nodes 2wv, 2wv+1; lane = output column
        float a0 = 0.f, a1 = 0.f;
        #pragma unroll
        for (int k = 0; k < D; ++k) {
            float wk = W[k * D + lane];         // L1-resident broadcast line
            a0 = fmaf(aggL[2 * wv][k], wk, a0);
            a1 = fmaf(aggL[2 * wv + 1][k], wk, a1);
        }
        float bl = bias[lane];
        if (cntL[2 * wv] > 0)     acc0 += a0 + bl;
        if (cntL[2 * wv + 1] > 0) acc1 += a1 + bl;
        __syncthreads();
    }

    size_t o0 = (size_t)(nodebase + 2 * wv) * D + lane;
    out[o0] = acc0;
    out[o0 + D] = acc1;
}

extern "C" void kernel_launch(void* const* d_in, const int* in_sizes, int n_in,
                              void* d_out, int out_size, void* d_ws, size_t ws_size,
                              hipStream_t stream) {
    const float* x = (const float*)d_in[0];
    const float* W[3] = {(const float*)d_in[1], (const float*)d_in[5], (const float*)d_in[9]};
    const float* b[3] = {(const float*)d_in[2], (const float*)d_in[6], (const float*)d_in[10]};
    const int* src[3] = {(const int*)d_in[3], (const int*)d_in[7], (const int*)d_in[11]};
    const int* dst[3] = {(const int*)d_in[4], (const int*)d_in[8], (const int*)d_in[12]};
    float* out = (float*)d_out;

    char* ws = (char*)d_ws;
    size_t o = 0;
    unsigned* bh = (unsigned*)(ws + o);     o += (size_t)3 * NBLK * NB * 4;   // 2.4 MB
    unsigned* total = (unsigned*)(ws + o);  o += (size_t)3 * NB * 4;
    unsigned* bases = (unsigned*)(ws + o);  o += (size_t)3 * NB * 4;
    unsigned* binned = (unsigned*)(ws + o); o += (size_t)3 * E_EDGES * 4;     // 19.2 MB
    unsigned* xh = binned;                  // overlay: binned dead after csr_kernel
    int* csr = (int*)(ws + o);              o += (size_t)3 * CSR_STRIDE * 4;  // 19.2 MB
    unsigned* off = (unsigned*)(ws + o);    o += (size_t)3 * N_NODES * 4;
    unsigned* cnt = (unsigned*)(ws + o);    o += (size_t)3 * N_NODES * 4;

    dim3 gE(NBLK, 3);
    hist_kernel<<<gE, 256, 0, stream>>>(dst[0], dst[1], dst[2], bh);
    dim3 gC(NB, 3);
    colscan_kernel<<<gC, 256, 0, stream>>>(bh, total);
    basescan_kernel<<<1, 256, 0, stream>>>(total, bases);
    bin_kernel<<<gE, 256, 0, stream>>>(src[0], src[1], src[2], dst[0], dst[1], dst[2],
                                       bh, bases, binned);
    dim3 gK(NB, 3);
    csr_kernel<<<gK, 256, 0, stream>>>(binned, total, bases, csr, off, cnt);
    convert_kernel<<<N_NODES * 32 / 256, 256, 0, stream>>>(x, xh);
    gather_fused_kernel<<<N_NODES / 8, 256, 0, stream>>>(xh, csr, off, cnt,
                                                         W[0], W[1], W[2], b[0], b[1], b[2], out);
}

// Round 10
// 276.624 us; speedup vs baseline: 6.2443x; 1.0653x over previous
//
#include <hip/hip_runtime.h>

#define N_NODES 100000
#define E_EDGES 1600000
#define D 64
#define NB 256                         // buckets
#define BW 391                         // bucket width: 391*256 = 100096 >= N
#define EPB 2048                       // edges per binning block
#define NBLK ((E_EDGES + EPB - 1) / EPB)   // 782
#define CAP 8192                       // per-bucket LDS staging capacity
#define CSR_STRIDE (E_EDGES + 64)

// ---- raw buffer load via hardware SRSRC (32-bit voffset, OOB clamps to 0)
// word3 = 0x00020000 is REQUIRED for raw untyped dword access (cdna4_isa SRD layout);
// flags=0 makes an invalid descriptor whose loads all return 0 (round-9 failure).
__device__ __forceinline__ __amdgpu_buffer_rsrc_t make_rsrc(const void* p, unsigned bytes) {
    return __builtin_amdgcn_make_buffer_rsrc(const_cast<void*>(p), /*stride*/(short)0,
                                             /*num_records*/(int)bytes,
                                             /*flags(word3)*/0x00020000);
}
__device__ __forceinline__ unsigned buf_ld(__amdgpu_buffer_rsrc_t r, int voff) {
    return __builtin_amdgcn_raw_buffer_load_b32(r, voff, 0, 0);
}

// ---- kA: per-block per-bucket histogram (coalesced writes, LDS atomics only)
__global__ __launch_bounds__(256) void hist_kernel(
    const int* __restrict__ dst0, const int* __restrict__ dst1, const int* __restrict__ dst2,
    unsigned* __restrict__ bh) {
    __shared__ unsigned h[NB];
    int t = threadIdx.x, blk = blockIdx.x, e = blockIdx.y;
    const int* dst = (e == 0) ? dst0 : (e == 1) ? dst1 : dst2;
    h[t] = 0;
    __syncthreads();
    int base = blk * EPB;
    #pragma unroll
    for (int r = 0; r < EPB / 256; ++r) {
        int i = base + r * 256 + t;
        if (i < E_EDGES) atomicAdd(&h[(unsigned)dst[i] / BW], 1u);
    }
    __syncthreads();
    bh[((size_t)e * NBLK + blk) * NB + t] = h[t];
}

// ---- kB: exclusive scan down each bucket column of bh (in place) + bucket totals
__global__ __launch_bounds__(256) void colscan_kernel(
    unsigned* __restrict__ bh, unsigned* __restrict__ total) {
    __shared__ unsigned sa[1024], sb[1024];
    int t = threadIdx.x, b = blockIdx.x, e = blockIdx.y;
    unsigned orig[4];
    #pragma unroll
    for (int k = 0; k < 4; ++k) {
        int i = t + k * 256;
        unsigned v = (i < NBLK) ? bh[((size_t)e * NBLK + i) * NB + b] : 0u;
        orig[k] = v;
        sa[i] = v;
    }
    __syncthreads();
    unsigned* s = sa; unsigned* d = sb;
    for (int st = 1; st < 1024; st <<= 1) {
        #pragma unroll
        for (int k = 0; k < 4; ++k) {
            int i = t + k * 256;
            d[i] = s[i] + ((i >= st) ? s[i - st] : 0u);
        }
        __syncthreads();
        unsigned* tmp = s; s = d; d = tmp;
    }
    #pragma unroll
    for (int k = 0; k < 4; ++k) {
        int i = t + k * 256;
        if (i < NBLK) bh[((size_t)e * NBLK + i) * NB + b] = s[i] - orig[k];
    }
    if (t == 0) total[e * NB + b] = s[1023];
}

// ---- kC: bucket bases = exclusive scan of totals (per etype)
__global__ __launch_bounds__(256) void basescan_kernel(
    const unsigned* __restrict__ total, unsigned* __restrict__ bases) {
    __shared__ unsigned sa[NB], sb[NB];
    int t = threadIdx.x;
    for (int e = 0; e < 3; ++e) {
        unsigned v = total[e * NB + t];
        sa[t] = v;
        __syncthreads();
        unsigned* s = sa; unsigned* d = sb;
        for (int st = 1; st < NB; st <<= 1) {
            d[t] = s[t] + ((t >= st) ? s[t - st] : 0u);
            __syncthreads();
            unsigned* tmp = s; s = d; d = tmp;
        }
        bases[e * NB + t] = s[t] - v;
        __syncthreads();
    }
}

// ---- kD: binning scatter; pos = base + block-offset + LDS rank; packed {dloc,src}
__global__ __launch_bounds__(256) void bin_kernel(
    const int* __restrict__ s0, const int* __restrict__ s1, const int* __restrict__ s2,
    const int* __restrict__ d0, const int* __restrict__ d1, const int* __restrict__ d2,
    const unsigned* __restrict__ bh, const unsigned* __restrict__ bases,
    unsigned* __restrict__ binned) {
    __shared__ unsigned basel[NB];
    __shared__ unsigned lc[NB];
    int t = threadIdx.x, blk = blockIdx.x, e = blockIdx.y;
    const int* src_ = (e == 0) ? s0 : (e == 1) ? s1 : s2;
    const int* dst_ = (e == 0) ? d0 : (e == 1) ? d1 : d2;
    basel[t] = bases[e * NB + t] + bh[((size_t)e * NBLK + blk) * NB + t];
    lc[t] = 0;
    __syncthreads();
    int base = blk * EPB;
    #pragma unroll
    for (int r = 0; r < EPB / 256; ++r) {
        int i = base + r * 256 + t;
        if (i < E_EDGES) {
            unsigned dd = (unsigned)dst_[i];
            unsigned b = dd / BW;
            unsigned dloc = dd - b * BW;
            unsigned rank = atomicAdd(&lc[b], 1u);
            binned[(size_t)e * E_EDGES + basel[b] + rank] = (unsigned)src_[i] | (dloc << 17);
        }
    }
}

// ---- kE: per-bucket CSR build fully in LDS, coalesced dump (grid.y = etype)
//      csr entries are PRE-SHIFTED row byte offsets: src*128
__global__ __launch_bounds__(256) void csr_kernel(
    const unsigned* __restrict__ binned, const unsigned* __restrict__ total,
    const unsigned* __restrict__ bases, int* __restrict__ csr,
    unsigned* __restrict__ off, unsigned* __restrict__ cnt) {
    __shared__ unsigned lh[512], sa[512], sb[512];
    __shared__ unsigned loff[BW + 1], lc[BW + 1];
    __shared__ int cl[CAP];
    int t = threadIdx.x, b = blockIdx.x, e = blockIdx.y;
    unsigned n = total[e * NB + b];
    unsigned g = bases[e * NB + b];
    lh[t] = 0; lh[t + 256] = 0;
    for (int j = t; j < BW + 1; j += 256) lc[j] = 0;
    __syncthreads();
    const unsigned* bp = binned + (size_t)e * E_EDGES + g;
    for (unsigned i = t; i < n; i += 256) atomicAdd(&lh[bp[i] >> 17], 1u);
    __syncthreads();
    sa[t] = lh[t]; sa[t + 256] = lh[t + 256];
    __syncthreads();
    unsigned* s = sa; unsigned* d = sb;
    for (int st = 1; st < 512; st <<= 1) {
        d[t] = s[t] + ((t >= st) ? s[t - st] : 0u);
        int i2 = t + 256;
        d[i2] = s[i2] + ((i2 >= st) ? s[i2 - st] : 0u);
        __syncthreads();
        unsigned* tmp = s; s = d; d = tmp;
    }
    if (t < BW + 1 - 256) loff[t + 256] = s[t + 256] - lh[t + 256];
    loff[t] = s[t] - lh[t];
    __syncthreads();
    int* csre = csr + (size_t)e * CSR_STRIDE;
    if (n <= CAP) {
        for (unsigned i = t; i < n; i += 256) {
            unsigned v = bp[i];
            unsigned dl = v >> 17;
            unsigned r = atomicAdd(&lc[dl], 1u);
            cl[loff[dl] + r] = (int)((v & 0x1FFFFu) << 7);
        }
        __syncthreads();
        for (unsigned i = t; i < n; i += 256) csre[g + i] = cl[i];
    } else {  // statistically impossible overflow fallback (correct, slower)
        for (unsigned i = t; i < n; i += 256) {
            unsigned v = bp[i];
            unsigned dl = v >> 17;
            unsigned r = atomicAdd(&lc[dl], 1u);
            csre[g + loff[dl] + r] = (int)((v & 0x1FFFFu) << 7);
        }
    }
    int node0 = b * BW;
    for (int j = t; j < BW; j += 256) {
        int nd = node0 + j;
        if (nd < N_NODES) {
            off[e * N_NODES + nd] = g + loff[j];
            cnt[e * N_NODES + nd] = lh[j];
        }
    }
}

// ---- convert x rows to packed bf16x2 (RNE): xh[n*32+p] = {bf16(x[2p]), bf16(x[2p+1])}
__global__ __launch_bounds__(256) void convert_kernel(const float* __restrict__ x,
                                                      unsigned* __restrict__ xh) {
    int i = blockIdx.x * 256 + threadIdx.x;    // pair index; grid covers N*32 exactly
    float2 v = *reinterpret_cast<const float2*>(x + (size_t)i * 2);
    unsigned lo = __float_as_uint(v.x), hi = __float_as_uint(v.y);
    lo = (lo + 0x7FFFu + ((lo >> 16) & 1u)) >> 16;
    hi = (hi + 0x7FFFu + ((hi >> 16) & 1u)) & 0xFFFF0000u;
    xh[i] = lo | hi;
}

#define UNPACK_ADD(u, s, tt) \
    s += __uint_as_float((u) << 16); tt += __uint_as_float((u) & 0xFFFF0000u);
#define UNPACK_FMA(m, u, s, tt) \
    s = fmaf(m, __uint_as_float((u) << 16), s); \
    tt = fmaf(m, __uint_as_float((u) & 0xFFFF0000u), tt);

// ---- fused gather+transform, all 3 etypes: half-wave (32 lanes) per node, lane = feature pair
__global__ __launch_bounds__(256) void gather_fused_kernel(
    const unsigned* __restrict__ xh, const int* __restrict__ csr,
    const unsigned* __restrict__ off, const unsigned* __restrict__ cnt,
    const float* __restrict__ W0, const float* __restrict__ W1, const float* __restrict__ W2,
    const float* __restrict__ b0, const float* __restrict__ b1, const float* __restrict__ b2,
    float* __restrict__ out) {
    __shared__ float aggL[3][8][D];
    __shared__ int cntL[3][8];

    int tid = threadIdx.x;
    int hw = tid >> 5, l = tid & 31;       // half-wave id (node slot), lane-in-half
    int wv = tid >> 6, lane = tid & 63;    // wave id, lane (transform phase)
    int nodebase = blockIdx.x * 8;
    int node = nodebase + hw;
    int l4 = l * 4;

    __amdgpu_buffer_rsrc_t srd = make_rsrc(xh, N_NODES * D * 2);   // bf16 table, bytes

    // ---- chase all 3 etypes back-to-back (no barriers: loads overlap across etypes)
    #pragma unroll
    for (int e = 0; e < 3; ++e) {
        unsigned c = cnt[e * N_NODES + node];
        const int* idx = csr + (size_t)e * CSR_STRIDE + off[e * N_NODES + node];

        float s0 = 0.f, s1 = 0.f, s2 = 0.f, s3 = 0.f;
        float s4 = 0.f, s5 = 0.f, s6 = 0.f, s7 = 0.f;
        float t0 = 0.f, t1 = 0.f, t2 = 0.f, t3 = 0.f;
        float t4 = 0.f, t5 = 0.f, t6 = 0.f, t7 = 0.f;

        unsigned fb = c >> 3;                // full 8-blocks
        for (unsigned blk = 0; blk < fb; ++blk) {
            const int* ip = idx + blk * 8;
            int i0 = ip[0], i1 = ip[1], i2 = ip[2], i3 = ip[3];
            int i4 = ip[4], i5 = ip[5], i6 = ip[6], i7 = ip[7];
            unsigned u0 = buf_ld(srd, i0 + l4);
            unsigned u1 = buf_ld(srd, i1 + l4);
            unsigned u2 = buf_ld(srd, i2 + l4);
            unsigned u3 = buf_ld(srd, i3 + l4);
            unsigned u4 = buf_ld(srd, i4 + l4);
            unsigned u5 = buf_ld(srd, i5 + l4);
            unsigned u6 = buf_ld(srd, i6 + l4);
            unsigned u7 = buf_ld(srd, i7 + l4);
            UNPACK_ADD(u0, s0, t0) UNPACK_ADD(u1, s1, t1)
            UNPACK_ADD(u2, s2, t2) UNPACK_ADD(u3, s3, t3)
            UNPACK_ADD(u4, s4, t4) UNPACK_ADD(u5, s5, t5)
            UNPACK_ADD(u6, s6, t6) UNPACK_ADD(u7, s7, t7)
        }
        if (c & 7) {                          // one predicated 8-wide tail block
            unsigned j = fb * 8;
            const int* ip = idx + j;          // reads past segment land in pad/neighbor entries;
            int i0 = ip[0], i1 = ip[1], i2 = ip[2], i3 = ip[3];   // garbage offsets OOB-clamp to 0
            int i4 = ip[4], i5 = ip[5], i6 = ip[6], i7 = ip[7];
            unsigned u0 = buf_ld(srd, i0 + l4);
            unsigned u1 = buf_ld(srd, i1 + l4);
            unsigned u2 = buf_ld(srd, i2 + l4);
            unsigned u3 = buf_ld(srd, i3 + l4);
            unsigned u4 = buf_ld(srd, i4 + l4);
            unsigned u5 = buf_ld(srd, i5 + l4);
            unsigned u6 = buf_ld(srd, i6 + l4);
            unsigned u7 = buf_ld(srd, i7 + l4);
            float m0 = (j + 0 < c) ? 1.f : 0.f;
            float m1 = (j + 1 < c) ? 1.f : 0.f;
            float m2 = (j + 2 < c) ? 1.f : 0.f;
            float m3 = (j + 3 < c) ? 1.f : 0.f;
            float m4 = (j + 4 < c) ? 1.f : 0.f;
            float m5 = (j + 5 < c) ? 1.f : 0.f;
            float m6 = (j + 6 < c) ? 1.f : 0.f;
            float m7 = (j + 7 < c) ? 1.f : 0.f;
            UNPACK_FMA(m0, u0, s0, t0) UNPACK_FMA(m1, u1, s1, t1)
            UNPACK_FMA(m2, u2, s2, t2) UNPACK_FMA(m3, u3, s3, t3)
            UNPACK_FMA(m4, u4, s4, t4) UNPACK_FMA(m5, u5, s5, t5)
            UNPACK_FMA(m6, u6, s6, t6) UNPACK_FMA(m7, u7, s7, t7)
        }
        float sc = c ? 1.0f / (float)c : 0.0f;
        float m0 = (((s0 + s1) + (s2 + s3)) + ((s4 + s5) + (s6 + s7))) * sc;
        float m1 = (((t0 + t1) + (t2 + t3)) + ((t4 + t5) + (t6 + t7))) * sc;
        *reinterpret_cast<float2*>(&aggL[e][hw][2 * l]) = make_float2(m0, m1);
        if (l == 0) cntL[e][hw] = (int)c;
    }
    __syncthreads();

    // ---- transform: wave wv handles nodes 2wv, 2wv+1; lane = output column; all 3 etypes
    float acc0 = 0.f, acc1 = 0.f;
    #pragma unroll
    for (int e = 0; e < 3; ++e) {
        const float* W = (e == 0) ? W0 : (e == 1) ? W1 : W2;
        const float* bias = (e == 0) ? b0 : (e == 1) ? b1 : b2;
        float a0 = 0.f, a1 = 0.f;
        #pragma unroll
        for (int k = 0; k < D; ++k) {
            float wk = W[k * D + lane];
            a0 = fmaf(aggL[e][2 * wv][k], wk, a0);
            a1 = fmaf(aggL[e][2 * wv + 1][k], wk, a1);
        }
        float bl = bias[lane];
        if (cntL[e][2 * wv] > 0)     acc0 += a0 + bl;
        if (cntL[e][2 * wv + 1] > 0) acc1 += a1 + bl;
    }

    size_t o0 = (size_t)(nodebase + 2 * wv) * D + lane;
    out[o0] = acc0;
    out[o0 + D] = acc1;
}

extern "C" void kernel_launch(void* const* d_in, const int* in_sizes, int n_in,
                              void* d_out, int out_size, void* d_ws, size_t ws_size,
                              hipStream_t stream) {
    const float* x = (const float*)d_in[0];
    const float* W[3] = {(const float*)d_in[1], (const float*)d_in[5], (const float*)d_in[9]};
    const float* b[3] = {(const float*)d_in[2], (const float*)d_in[6], (const float*)d_in[10]};
    const int* src[3] = {(const int*)d_in[3], (const int*)d_in[7], (const int*)d_in[11]};
    const int* dst[3] = {(const int*)d_in[4], (const int*)d_in[8], (const int*)d_in[12]};
    float* out = (float*)d_out;

    char* ws = (char*)d_ws;
    size_t o = 0;
    unsigned* bh = (unsigned*)(ws + o);     o += (size_t)3 * NBLK * NB * 4;   // 2.4 MB
    unsigned* total = (unsigned*)(ws + o);  o += (size_t)3 * NB * 4;
    unsigned* bases = (unsigned*)(ws + o);  o += (size_t)3 * NB * 4;
    unsigned* binned = (unsigned*)(ws + o); o += (size_t)3 * E_EDGES * 4;     // 19.2 MB
    unsigned* xh = binned;                  // overlay: binned dead after csr_kernel
    int* csr = (int*)(ws + o);              o += (size_t)3 * CSR_STRIDE * 4;  // 19.2 MB
    unsigned* off = (unsigned*)(ws + o);    o += (size_t)3 * N_NODES * 4;
    unsigned* cnt = (unsigned*)(ws + o);    o += (size_t)3 * N_NODES * 4;

    dim3 gE(NBLK, 3);
    hist_kernel<<<gE, 256, 0, stream>>>(dst[0], dst[1], dst[2], bh);
    dim3 gC(NB, 3);
    colscan_kernel<<<gC, 256, 0, stream>>>(bh, total);
    basescan_kernel<<<1, 256, 0, stream>>>(total, bases);
    bin_kernel<<<gE, 256, 0, stream>>>(src[0], src[1], src[2], dst[0], dst[1], dst[2],
                                       bh, bases, binned);
    dim3 gK(NB, 3);
    csr_kernel<<<gK, 256, 0, stream>>>(binned, total, bases, csr, off, cnt);
    convert_kernel<<<N_NODES * 32 / 256, 256, 0, stream>>>(x, xh);
    gather_fused_kernel<<<N_NODES / 8, 256, 0, stream>>>(xh, csr, off, cnt,
                                                         W[0], W[1], W[2], b[0], b[1], b[2], out);
}